// Round 12
// baseline (1280.991 us; speedup 1.0000x reference)
//
#include <hip/hip_runtime.h>
#include <hip/hip_cooperative_groups.h>
#include <math.h>

// DeltaLM: B=4 T=2048 D=512 H=2048 L=3 V=256
// decay einsum == geometric scan S[i]=h[i]+w*S[i-1], w=exp(-softplus(k)).
// Round 12: GEMMs are at the m97 plateau (R8/R9/R10 falsified occupancy/
// L2/LDS-pipe theories). Remaining lever: dispatch count. Cooperative
// mega-fusion: prologue chain (embed+cumprod+tanh -> partA -> prefix ->
// bd_apply -> prefix -> mag_scan_ln(0)) = ONE hipLaunchCooperativeKernel
// with grid.sync(); per-layer (prefix -> mag_scan_ln) likewise. 17 -> 11
// dispatches; th lives in LDS only; l=0 magscan reuses h from registers.

namespace cg = cooperative_groups;

constexpr int Bc = 4, Tc = 2048, Dc = 512, Hc = 2048, Vc = 256;
constexpr int TSF = 16, NCF = 128, WARM = 20;

typedef __attribute__((ext_vector_type(8))) short short8;
typedef __attribute__((ext_vector_type(4))) float f32x4;

__device__ inline unsigned short f2bf(float f) {  // RNE fp32->bf16
  unsigned int u = __float_as_uint(f);
  u += 0x7fffu + ((u >> 16) & 1u);
  return (unsigned short)(u >> 16);
}

__device__ inline void gload_lds16(const void* g, void* l) {
  __builtin_amdgcn_global_load_lds(
      (const __attribute__((address_space(1))) void*)g,
      (__attribute__((address_space(3))) void*)l, 16, 0, 0);
}

// gelu(z) = 0.5 z (1+erf(z/sqrt2)); erf via A&S 7.1.26, |eps|<=1.5e-7
__device__ inline float gelu_f(float z) {
  float x = z * 0.707106781186547524f;
  float ax = fabsf(x);
  float t = 1.0f / (1.0f + 0.3275911f * ax);
  float poly = t*(0.254829592f + t*(-0.284496736f + t*(1.421413741f +
               t*(-1.453152027f + t*1.061405429f))));
  float er = 1.0f - poly * __expf(-ax*ax);
  er = copysignf(er, x);
  return 0.5f * z * (1.0f + er);
}

// ---------- merged weight prep: W1t, W2t (transpose->bf16) + emb ----------
__device__ inline void tr32(const float* Wl, unsigned short* Wtl,
                            int R, int C, int c0, int r0, int tid,
                            float (*tile)[33]) {
  int tx = tid & 31, ty = tid >> 5;
  for (int i = ty; i < 32; i += 8)
    tile[i][tx] = Wl[(size_t)(r0+i)*C + (c0+tx)];
  __syncthreads();
  for (int i = ty; i < 32; i += 8)
    Wtl[(size_t)(c0+i)*R + (r0+tx)] = f2bf(tile[tx][i]);
}

__global__ __launch_bounds__(256) void wprep(
    const float* __restrict__ W1, unsigned short* __restrict__ W1t,
    const float* __restrict__ W2, unsigned short* __restrict__ W2t,
    const float* __restrict__ embed, unsigned short* __restrict__ emb)
{
  __shared__ float tile[32][33];
  int bid = blockIdx.x, tid = threadIdx.x;
  if (bid < 3072) {            // W1: (L, Dc, Hc) -> (L, Hc, Dc) bf16
    int l = bid >> 10, rem = bid & 1023;
    int cx = rem & 63, ry = rem >> 6;
    tr32(W1 + (size_t)l*Dc*Hc, W1t + (size_t)l*Dc*Hc, Dc, Hc,
         cx*32, ry*32, tid, tile);
  } else if (bid < 6144) {     // W2: (L, Hc, Dc) -> (L, Dc, Hc) bf16
    int b2 = bid - 3072;
    int l = b2 >> 10, rem = b2 & 1023;
    int cx = rem & 15, ry = rem >> 4;
    tr32(W2 + (size_t)l*Hc*Dc, W2t + (size_t)l*Hc*Dc, Hc, Dc,
         cx*32, ry*32, tid, tile);
  } else {                     // emb: fp32 -> bf16
    int i = (bid - 6144)*256 + tid;
    if (i < Vc*Dc) emb[i] = f2bf(embed[i]);
  }
}

// ---------- wave-scan helper: exclusive prefix over 128 chunks ----------
__device__ inline void prefix_scan_pair(float* part, int pair, int lane) {
  int b = pair >> 9, d = pair & 511;
  size_t i0 = ((size_t)b*NCF + 2*lane)*Dc + d;
  float v0 = part[i0];
  float v1 = part[i0 + Dc];
  float ps = v0 + v1;
  float incl = ps;
  #pragma unroll
  for (int off=1; off<64; off<<=1) {
    float t = __shfl_up(incl, off);
    if (lane >= off) incl += t;
  }
  float excl = incl - ps;
  part[i0]      = excl;
  part[i0 + Dc] = excl + v0;
}

// ---------- mag+scan+LN epilogue (shared by both cooperative kernels) ----
// hv[] = h values for this chunk (already in registers). Writes yb.
__device__ inline void mag_scan_ln_body(
    float* hv, const float* hbase, float accp, int t0, int c, int b, int d,
    int lane, int wv, float w,
    const float* g, const float* bt, int l, unsigned short* yb,
    float (*redA)[TSF], float (*redB)[TSF],
    float* mag, float* muS, float* rsS)
{
  float acc = accp;
  float hp = (t0 > 0) ? hbase[(size_t)(t0-1)*Dc] : 0.f;
  #pragma unroll
  for (int t=0;t<TSF;++t) {
    acc += hv[t];
    float diff = acc - hp;
    hp = hv[t];
    float s = diff * diff;
    #pragma unroll
    for (int off=32; off; off>>=1) s += __shfl_down(s, off);
    if (!lane) redA[wv][t] = s;
  }
  int ts = t0 - WARM; if (ts < 0) ts = 0;
  float s = 0.f;
  for (int t=ts; t<t0; ++t) s = hbase[(size_t)t*Dc] + w*s;
  __syncthreads();
  if (d < TSF) {
    float m = 0.f;
    #pragma unroll
    for (int w2=0;w2<8;++w2) m += redA[w2][d];
    mag[d] = sqrtf(m);
  }
  __syncthreads();
  #pragma unroll
  for (int t=0;t<TSF;++t) {
    s = hv[t] + w * s;
    float cv = mag[t] * fabsf(s);
    hv[t] = cv;
    float s1 = cv, s2 = cv * cv;
    #pragma unroll
    for (int off=32; off; off>>=1) {
      s1 += __shfl_down(s1, off);
      s2 += __shfl_down(s2, off);
    }
    if (!lane) { redA[wv][t] = s1; redB[wv][t] = s2; }
  }
  __syncthreads();
  if (d < TSF) {
    float m1 = 0.f, m2 = 0.f;
    #pragma unroll
    for (int w2=0;w2<8;++w2) { m1 += redA[w2][d]; m2 += redB[w2][d]; }
    float mu = m1 * (1.f/Dc);
    float var = fmaxf(m2 * (1.f/Dc) - mu*mu, 0.f);
    muS[d] = mu;
    rsS[d] = rsqrtf(var + 1e-3f);
  }
  __syncthreads();
  float gv = g[l*Dc + d], bv = bt[l*Dc + d];
  unsigned short* yp = yb + ((size_t)b*Tc + t0)*Dc + d;
  #pragma unroll
  for (int t=0;t<TSF;++t)
    yp[(size_t)t*Dc] = f2bf((hv[t] - muS[t]) * rsS[t] * gv + bv);
}

__device__ inline float decay_w(const float* kvec, int l) {
  float kk = kvec[l];
  float sp = kk > 0.f ? kk + log1pf(expf(-kk)) : log1pf(expf(kk));
  return expf(-sp);
}

// ---------- cooperative prologue: embed+cumprod+tanh (LDS) -> partA ->
// prefix -> bd_apply (h, partB) -> prefix -> mag_scan_ln(l=0) -> yb -------
__global__ __launch_bounds__(512, 4) void coop_prologue(
    const int* __restrict__ x, const float* __restrict__ embed,
    float* __restrict__ partA, float* __restrict__ partB,
    float* __restrict__ h, const float* __restrict__ kvec,
    const float* __restrict__ g, const float* __restrict__ bt,
    unsigned short* __restrict__ yb)
{
  cg::grid_group gg = cg::this_grid();
  __shared__ float thL[TSF][Dc];               // 32 KB
  __shared__ float redA[8][TSF], redB[8][TSF];
  __shared__ float mag[TSF], muS[TSF], rsS[TSF];
  int c = blockIdx.x, b = blockIdx.y;
  int tid = threadIdx.x, wv = tid >> 6, lane = tid & 63;

  // phase 1: embed gather + cumprod(feature) + tanh, 2 tokens per wave
  #pragma unroll
  for (int rep=0; rep<2; ++rep) {
    int tk = wv + rep*8;
    int token = b*Tc + c*TSF + tk;
    int row = x[token];
    const float* e = embed + (size_t)row * Dc + lane * 8;
    float v[8];
    {
      float4 a = *(const float4*)e;
      float4 bb = *(const float4*)(e + 4);
      v[0]=a.x; v[1]=a.y; v[2]=a.z; v[3]=a.w;
      v[4]=bb.x; v[5]=bb.y; v[6]=bb.z; v[7]=bb.w;
    }
    float p = v[0];
    #pragma unroll
    for (int j=1;j<8;++j) p *= v[j];
    float incl = p;
    #pragma unroll
    for (int off=1; off<64; off<<=1) {
      float t = __shfl_up(incl, off);
      if (lane >= off) incl *= t;
    }
    float excl = __shfl_up(incl, 1);
    if (lane == 0) excl = 1.0f;
    float cc = excl;
    #pragma unroll
    for (int j=0;j<8;++j) { cc *= v[j]; thL[tk][lane*8+j] = tanhf(cc); }
  }
  __syncthreads();
  // phase 1b: partA chunk sums
  int d = tid;
  {
    float s = 0.f;
    #pragma unroll
    for (int t=0;t<TSF;++t) s += thL[t][d];
    partA[((size_t)b*NCF + c)*Dc + d] = s;
  }
  __threadfence();
  gg.sync();
  // phase 2: exclusive prefix of partA (2048 waves needed, 4096 available)
  int gw = (b*NCF + c)*8 + wv;
  if (gw < 2048) prefix_scan_pair(partA, gw, lane);
  __threadfence();
  gg.sync();
  // phase 3: bd_apply -- h = embed[x]*(1+cumsum(th)); partB chunk sums
  float hv[TSF];
  {
    float acc = partA[((size_t)b*NCF + c)*Dc + d];
    float hsum = 0.f;
    #pragma unroll
    for (int t=0;t<TSF;++t) {
      int tt = c*TSF + t;
      acc += thL[t][d];
      int row = x[b*Tc + tt];
      float e = embed[(size_t)row*Dc + d];
      hv[t] = e * (1.0f + acc);
      h[((size_t)b*Tc + tt)*Dc + d] = hv[t];
      hsum += hv[t];
    }
    partB[((size_t)b*NCF + c)*Dc + d] = hsum;
  }
  __threadfence();
  gg.sync();
  // phase 4: exclusive prefix of partB
  if (gw < 2048) prefix_scan_pair(partB, gw, lane);
  __threadfence();
  gg.sync();
  // phase 5: mag + geometric scan + LN for l=0 (hv already in registers)
  float w = decay_w(kvec, 0);
  float accp = partB[((size_t)b*NCF + c)*Dc + d];
  const float* hbase = h + (size_t)b*Tc*Dc + d;
  mag_scan_ln_body(hv, hbase, accp, c*TSF, c, b, d, lane, wv, w,
                   g, bt, 0, yb, redA, redB, mag, muS, rsS);
}

// ---------- cooperative per-layer: prefix(partB) -> mag_scan_ln(l) -------
__global__ __launch_bounds__(512, 4) void coop_magscan(
    float* __restrict__ partB, const float* __restrict__ h,
    const float* __restrict__ kvec, int l,
    const float* __restrict__ g, const float* __restrict__ bt,
    unsigned short* __restrict__ yb)
{
  cg::grid_group gg = cg::this_grid();
  __shared__ float redA[8][TSF], redB[8][TSF];
  __shared__ float mag[TSF], muS[TSF], rsS[TSF];
  int c = blockIdx.x, b = blockIdx.y;
  int tid = threadIdx.x, wv = tid >> 6, lane = tid & 63;
  int gw = (b*NCF + c)*8 + wv;
  if (gw < 2048) prefix_scan_pair(partB, gw, lane);
  __threadfence();
  gg.sync();
  int d = tid, t0 = c*TSF;
  const float* hbase = h + (size_t)b*Tc*Dc + d;
  float hv[TSF];
  #pragma unroll
  for (int t=0;t<TSF;++t) hv[t] = hbase[(size_t)(t0+t)*Dc];
  float w = decay_w(kvec, l);
  float accp = partB[((size_t)b*NCF + c)*Dc + d];
  mag_scan_ln_body(hv, hbase, accp, t0, c, b, d, lane, wv, w,
                   g, bt, l, yb, redA, redB, mag, muS, rsS);
}

template<int CH> __device__ inline int swz(int row) {
  if constexpr (CH == 8) return row & 7;
  else return (row & 3) ^ ((row >> 3) & 1);
}

// ---------- bf16 MFMA GEMM, dbuf LDS, 1 barrier/K-step, XCD supertiles ----
// EPI 0: Cb=bf16(gelu(z+bias)); 1: C+=z+bias (+ chunk partials, opt Cb);
// 2: C=z.
template<int EPI, int TM, int TN, int BK>
__global__ __launch_bounds__(256) void mgemm(
    const unsigned short* __restrict__ A,
    const unsigned short* __restrict__ Bt,
    const float* __restrict__ bias,
    float* __restrict__ C, unsigned short* __restrict__ Cb,
    float* __restrict__ part,
    int N, int K, int nrow)
{
  constexpr int CH = BK / 8;
  constexpr int PA = TM*CH/256, PB = TN*CH/256;
  constexpr int WM = TM/2, WN = TN/2;
  constexpr int AM = WM/16, AN = WN/16;
  constexpr int NKH = BK/32;
  constexpr int ASTG = TM*BK, BSTG = TN*BK;
  __shared__ unsigned short As[2*ASTG];
  __shared__ unsigned short Bs[2*BSTG];
  int tid = threadIdx.x;
  int lane = tid & 63, w = tid >> 6;
  int wr = w >> 1, wc = w & 1;
  int bid = blockIdx.x;
  int xcd = bid & 7, i = bid >> 3;
  int npx = nrow >> 3;
  int m0 = (xcd * npx + (i % npx)) * TM;
  int n0 = (i / npx) * TN;

  const unsigned short* ag[PA];
  const unsigned short* bg[PB];
  int aldst[PA], bldst[PB];
  #pragma unroll
  for (int p=0;p<PA;++p) {
    int ci = p*256 + tid;
    int row = ci / CH, cp = ci % CH;
    int cg = cp ^ swz<CH>(row);
    ag[p] = A + (size_t)(m0+row)*K + cg*8;
    aldst[p] = (p*256 + w*64)*8;
  }
  #pragma unroll
  for (int p=0;p<PB;++p) {
    int ci = p*256 + tid;
    int row = ci / CH, cp = ci % CH;
    int cg = cp ^ swz<CH>(row);
    bg[p] = Bt + (size_t)(n0+row)*K + cg*8;
    bldst[p] = (p*256 + w*64)*8;
  }

  int r = lane & 15, quad = lane >> 4;
  int aoff[NKH][AM], boff[NKH][AN];
  #pragma unroll
  for (int kh=0;kh<NKH;++kh) {
    int cb = kh*4 + quad;
    #pragma unroll
    for (int i2=0;i2<AM;++i2)
      aoff[kh][i2] = (wr*WM + i2*16 + r)*BK + ((cb ^ swz<CH>(r)) & (CH-1))*8;
    #pragma unroll
    for (int j=0;j<AN;++j)
      boff[kh][j] = (wc*WN + j*16 + r)*BK + ((cb ^ swz<CH>(r)) & (CH-1))*8;
  }

  f32x4 acc[AM][AN];
  #pragma unroll
  for (int i2=0;i2<AM;++i2)
    #pragma unroll
    for (int j=0;j<AN;++j)
      acc[i2][j] = (f32x4){0.f,0.f,0.f,0.f};

  #pragma unroll
  for (int p=0;p<PA;++p) gload_lds16(ag[p], &As[aldst[p]]);
  #pragma unroll
  for (int p=0;p<PB;++p) gload_lds16(bg[p], &Bs[bldst[p]]);

  int nk = K / BK;
  for (int ki = 0; ki < nk; ++ki) {
    __syncthreads();
    int cur = ki & 1, nxt = cur ^ 1;
    if (ki + 1 < nk) {
      int kk = (ki + 1) * BK;
      #pragma unroll
      for (int p=0;p<PA;++p) gload_lds16(ag[p] + kk, &As[nxt*ASTG + aldst[p]]);
      #pragma unroll
      for (int p=0;p<PB;++p) gload_lds16(bg[p] + kk, &Bs[nxt*BSTG + bldst[p]]);
    }
    #pragma unroll
    for (int kh=0;kh<NKH;++kh) {
      short8 af[AM], bfr[AN];
      #pragma unroll
      for (int i2=0;i2<AM;++i2) af[i2] = *(const short8*)&As[cur*ASTG + aoff[kh][i2]];
      #pragma unroll
      for (int j=0;j<AN;++j) bfr[j] = *(const short8*)&Bs[cur*BSTG + boff[kh][j]];
      #pragma unroll
      for (int i2=0;i2<AM;++i2)
        #pragma unroll
        for (int j=0;j<AN;++j)
          acc[i2][j] = __builtin_amdgcn_mfma_f32_16x16x32_bf16(af[i2], bfr[j], acc[i2][j], 0, 0, 0);
    }
  }

  #pragma unroll
  for (int i2=0;i2<AM;++i2) {
    int rowb = m0 + wr*WM + i2*16 + quad*4;
    #pragma unroll
    for (int j=0;j<AN;++j) {
      int col = n0 + wc*WN + j*16 + r;
      float bv = 0.f;
      if (EPI != 2) bv = bias[col];
      float ps = 0.f;
      #pragma unroll
      for (int reg=0;reg<4;++reg) {
        size_t idx = (size_t)(rowb + reg) * N + col;
        float z = acc[i2][j][reg] + bv;
        if (EPI == 0) {
          Cb[idx] = f2bf(gelu_f(z));
        } else if (EPI == 1) {
          float hv = C[idx] + z;
          C[idx] = hv;
          ps += hv;
          if (Cb) Cb[idx] = f2bf(hv);
        } else {
          C[idx] = z;
        }
      }
      if (EPI == 1 && part) {
        ps += __shfl_xor(ps, 16);
        ps += __shfl_xor(ps, 32);
        if (quad == 0) {
          int chunk = (m0 + wr*WM + i2*16) >> 4;   // TSF=16
          part[(size_t)chunk * N + col] = ps;
        }
      }
    }
  }
}

extern "C" void kernel_launch(void* const* d_in, const int* in_sizes, int n_in,
                              void* d_out, int out_size, void* d_ws, size_t ws_size,
                              hipStream_t stream) {
  const int*   x     = (const int*)  d_in[0];
  const float* embed = (const float*)d_in[1];
  const float* kvec  = (const float*)d_in[2];
  const float* g     = (const float*)d_in[3];
  const float* bt    = (const float*)d_in[4];
  const float* W1    = (const float*)d_in[5];
  const float* b1    = (const float*)d_in[6];
  const float* W2    = (const float*)d_in[7];
  const float* b2    = (const float*)d_in[8];
  float* out = (float*)d_out;

  const size_t NTD = (size_t)Bc * Tc * Dc;   // 4,194,304
  const size_t NTH = (size_t)Bc * Tc * Hc;   // 16,777,216
  char* wsb = (char*)d_ws;
  float* h      = (float*)wsb;                wsb += NTD*4;               // 16MB
  float* partA  = (float*)wsb;                wsb += (size_t)Bc*NCF*Dc*4; // 1MB
  float* partB  = (float*)wsb;                wsb += (size_t)Bc*NCF*Dc*4; // 1MB
  unsigned short* yb   = (unsigned short*)wsb; wsb += NTD*2;              // 8MB
  unsigned short* a1b  = (unsigned short*)wsb; wsb += NTH*2;              // 32MB
  unsigned short* hb   = (unsigned short*)wsb; wsb += NTD*2;              // 8MB
  unsigned short* W1t  = (unsigned short*)wsb; wsb += (size_t)3*Dc*Hc*2;  // 6MB
  unsigned short* W2t  = (unsigned short*)wsb; wsb += (size_t)3*Dc*Hc*2;  // 6MB
  unsigned short* emb  = (unsigned short*)wsb; wsb += (size_t)Vc*Dc*2;

  // merged weight prep (1 dispatch)
  wprep<<<dim3(6144 + (Vc*Dc+255)/256), 256, 0, stream>>>(
      W1, W1t, W2, W2t, embed, emb);

  // cooperative prologue: 5 dispatches -> 1
  {
    void* args[] = { (void*)&x, (void*)&embed, (void*)&partA, (void*)&partB,
                     (void*)&h, (void*)&kvec, (void*)&g, (void*)&bt,
                     (void*)&yb };
    hipLaunchCooperativeKernel((void*)coop_prologue, dim3(NCF, Bc),
                               dim3(512), args, 0, stream);
  }

  for (int l = 0; l < 3; ++l) {
    if (l > 0) {
      // cooperative: prefix(partB) + mag_scan_ln(l) in one launch
      int ll = l;
      void* args[] = { (void*)&partB, (void*)&h, (void*)&kvec, (void*)&ll,
                       (void*)&g, (void*)&bt, (void*)&yb };
      hipLaunchCooperativeKernel((void*)coop_magscan, dim3(NCF, Bc),
                                 dim3(512), args, 0, stream);
    }
    // z = gelu(y @ W1 + b1): M=8192 N=2048 K=512; 64x64 BK=64 -> 4096 blocks
    mgemm<0,64,64,64><<<dim3(128*(Hc/64)), 256, 0, stream>>>(
        yb, W1t + (size_t)l*Hc*Dc, b1 + (size_t)l*Hc, nullptr, a1b, nullptr,
        Hc, Dc, 128);
    // h += z @ W2 + b2 (+ h chunk partials): 64x64 tile, BK=64 -> 1024 blocks
    mgemm<1,64,64,64><<<dim3(128*(Dc/64)), 256, 0, stream>>>(
        a1b, W2t + (size_t)l*Dc*Hc, b2 + (size_t)l*Dc, h,
        (l == 2) ? hb : nullptr, (l < 2) ? partB : nullptr, Dc, Hc, 128);
  }
  // out = h @ embed^T: M=8192 N=256 K=512; 64x64 tiles, nrow=128
  mgemm<2,64,64,32><<<dim3(128*(Vc/64)), 256, 0, stream>>>(
      hb, emb, nullptr, out, nullptr, nullptr, Vc, Dc, 128);
}

// Round 13
// 423.416 us; speedup vs baseline: 3.0254x; 3.0254x over previous
//
#include <hip/hip_runtime.h>
#include <math.h>

// DeltaLM: B=4 T=2048 D=512 H=2048 L=3 V=256
// decay einsum == geometric scan S[i]=h[i]+w*S[i-1], w=exp(-softplus(k)).
// Round 13: R12 cooperative grid.sync() cost ~600us/launch -> REVERTED to
// R11 structure. Kept one safe simplification: part_prefix dispatches (4)
// deleted; consumers compute the exclusive chunk-prefix inline (ILP-unrolled
// O(c) loop over L2-hot 1MB partials; 512 blocks hide the latency).

constexpr int Bc = 4, Tc = 2048, Dc = 512, Hc = 2048, Vc = 256;
constexpr int TSF = 16, NCF = 128, WARM = 20;

typedef __attribute__((ext_vector_type(8))) short short8;
typedef __attribute__((ext_vector_type(4))) float f32x4;

__device__ inline unsigned short f2bf(float f) {  // RNE fp32->bf16
  unsigned int u = __float_as_uint(f);
  u += 0x7fffu + ((u >> 16) & 1u);
  return (unsigned short)(u >> 16);
}

__device__ inline void gload_lds16(const void* g, void* l) {
  __builtin_amdgcn_global_load_lds(
      (const __attribute__((address_space(1))) void*)g,
      (__attribute__((address_space(3))) void*)l, 16, 0, 0);
}

// gelu(z) = 0.5 z (1+erf(z/sqrt2)); erf via A&S 7.1.26, |eps|<=1.5e-7
__device__ inline float gelu_f(float z) {
  float x = z * 0.707106781186547524f;
  float ax = fabsf(x);
  float t = 1.0f / (1.0f + 0.3275911f * ax);
  float poly = t*(0.254829592f + t*(-0.284496736f + t*(1.421413741f +
               t*(-1.453152027f + t*1.061405429f))));
  float er = 1.0f - poly * __expf(-ax*ax);
  er = copysignf(er, x);
  return 0.5f * z * (1.0f + er);
}

// exclusive prefix over chunks [0,c) for feature d: ILP-unrolled, L2-hot
__device__ inline float chunk_prefix(const float* __restrict__ part,
                                     int b, int c, int d) {
  float a0 = 0.f, a1 = 0.f, a2 = 0.f, a3 = 0.f;
  const float* p = part + (size_t)b*NCF*Dc + d;
  int cc = 0;
  for (; cc + 4 <= c; cc += 4) {
    a0 += p[(size_t)(cc+0)*Dc];
    a1 += p[(size_t)(cc+1)*Dc];
    a2 += p[(size_t)(cc+2)*Dc];
    a3 += p[(size_t)(cc+3)*Dc];
  }
  for (; cc < c; ++cc) a0 += p[(size_t)cc*Dc];
  return (a0 + a1) + (a2 + a3);
}

// ---------- merged weight prep: W1t, W2t (transpose->bf16) + emb ----------
__device__ inline void tr32(const float* Wl, unsigned short* Wtl,
                            int R, int C, int c0, int r0, int tid,
                            float (*tile)[33]) {
  int tx = tid & 31, ty = tid >> 5;
  for (int i = ty; i < 32; i += 8)
    tile[i][tx] = Wl[(size_t)(r0+i)*C + (c0+tx)];
  __syncthreads();
  for (int i = ty; i < 32; i += 8)
    Wtl[(size_t)(c0+i)*R + (r0+tx)] = f2bf(tile[tx][i]);
}

__global__ __launch_bounds__(256) void wprep(
    const float* __restrict__ W1, unsigned short* __restrict__ W1t,
    const float* __restrict__ W2, unsigned short* __restrict__ W2t,
    const float* __restrict__ embed, unsigned short* __restrict__ emb)
{
  __shared__ float tile[32][33];
  int bid = blockIdx.x, tid = threadIdx.x;
  if (bid < 3072) {            // W1: (L, Dc, Hc) -> (L, Hc, Dc) bf16
    int l = bid >> 10, rem = bid & 1023;
    int cx = rem & 63, ry = rem >> 6;
    tr32(W1 + (size_t)l*Dc*Hc, W1t + (size_t)l*Dc*Hc, Dc, Hc,
         cx*32, ry*32, tid, tile);
  } else if (bid < 6144) {     // W2: (L, Hc, Dc) -> (L, Dc, Hc) bf16
    int b2 = bid - 3072;
    int l = b2 >> 10, rem = b2 & 1023;
    int cx = rem & 15, ry = rem >> 4;
    tr32(W2 + (size_t)l*Hc*Dc, W2t + (size_t)l*Hc*Dc, Hc, Dc,
         cx*32, ry*32, tid, tile);
  } else {                     // emb: fp32 -> bf16
    int i = (bid - 6144)*256 + tid;
    if (i < Vc*Dc) emb[i] = f2bf(embed[i]);
  }
}

// ---------- embed gather + cumprod + tanh + chunk sums (fused) ----------
__global__ __launch_bounds__(1024) void embed_part(
    const int* __restrict__ x, const float* __restrict__ embed,
    float* __restrict__ th, float* __restrict__ partA)
{
  int c = blockIdx.x, b = blockIdx.y;
  int wv = threadIdx.x >> 6, lane = threadIdx.x & 63;
  int token = b*Tc + c*TSF + wv;
  int row = x[token];
  const float* e = embed + (size_t)row * Dc + lane * 8;
  float v[8];
  {
    float4 a = *(const float4*)e;
    float4 bb = *(const float4*)(e + 4);
    v[0]=a.x; v[1]=a.y; v[2]=a.z; v[3]=a.w;
    v[4]=bb.x; v[5]=bb.y; v[6]=bb.z; v[7]=bb.w;
  }
  float p = v[0];
  #pragma unroll
  for (int j=1;j<8;++j) p *= v[j];
  float incl = p;
  #pragma unroll
  for (int off=1; off<64; off<<=1) {
    float t = __shfl_up(incl, off);
    if (lane >= off) incl *= t;
  }
  float excl = __shfl_up(incl, 1);
  if (lane == 0) excl = 1.0f;
  float cc = excl;
  float o[8];
  #pragma unroll
  for (int j=0;j<8;++j) { cc *= v[j]; o[j] = tanhf(cc); }
  float* dst = th + (size_t)token * Dc + lane * 8;
  *(float4*)dst     = make_float4(o[0],o[1],o[2],o[3]);
  *(float4*)(dst+4) = make_float4(o[4],o[5],o[6],o[7]);
  __syncthreads();
  int d = threadIdx.x;
  if (d < Dc) {
    const float* pp = th + ((size_t)b*Tc + c*TSF)*Dc + d;
    float s = 0.f;
    #pragma unroll
    for (int t=0;t<TSF;++t) s += pp[(size_t)t*Dc];
    partA[((size_t)b*NCF + c)*Dc + d] = s;
  }
}

// ---------- bd = cumsum_t(th); h = embed[x]*(1+bd); writes h chunk sum ----
// partA holds RAW chunk sums; exclusive prefix computed inline.
__global__ __launch_bounds__(512) void bd_apply(
    const float* __restrict__ th, const float* __restrict__ partA,
    const int* __restrict__ x, const float* __restrict__ embed,
    float* __restrict__ h, float* __restrict__ partB)
{
  int c = blockIdx.x, b = blockIdx.y, d = threadIdx.x;
  float acc = chunk_prefix(partA, b, c, d);
  float hsum = 0.f;
  #pragma unroll
  for (int t=0;t<TSF;++t) {
    int tt = c*TSF + t;
    size_t idx = ((size_t)b*Tc + tt)*Dc + d;
    acc += th[idx];
    int row = x[b*Tc + tt];
    float e = embed[(size_t)row*Dc + d];
    float hv = e * (1.0f + acc);
    h[idx] = hv;
    hsum += hv;
  }
  partB[((size_t)b*NCF + c)*Dc + d] = hsum;        // raw chunk sum (h)
}

// ---------- fused: inline prefix + mag + geometric scan + LN -> bf16 ----
// partB holds RAW h chunk sums (from bd_apply or mgemm<1> epilogue).
__global__ __launch_bounds__(512) void mag_scan_ln(
    const float* __restrict__ h, const float* __restrict__ partB,
    const float* __restrict__ kvec, int l,
    const float* __restrict__ g, const float* __restrict__ bt,
    unsigned short* __restrict__ yb)
{
  __shared__ float redA[8][TSF];
  __shared__ float redB[8][TSF];
  __shared__ float mag[TSF], muS[TSF], rsS[TSF];
  int c = blockIdx.x, b = blockIdx.y, d = threadIdx.x;
  int lane = d & 63, wv = d >> 6;
  float acc = chunk_prefix(partB, b, c, d);
  int t0 = c * TSF;
  const float* hbase = h + (size_t)b*Tc*Dc + d;
  float hp = (t0 > 0) ? hbase[(size_t)(t0-1)*Dc] : 0.f;
  float hv[TSF];
  #pragma unroll
  for (int t=0;t<TSF;++t) {
    hv[t] = hbase[(size_t)(t0+t)*Dc];
    acc += hv[t];
    float diff = acc - hp;
    hp = hv[t];
    float s = diff * diff;
    #pragma unroll
    for (int off=32; off; off>>=1) s += __shfl_down(s, off);
    if (!lane) redA[wv][t] = s;
  }
  float kk = kvec[l];
  float sp = kk > 0.f ? kk + log1pf(expf(-kk)) : log1pf(expf(kk));
  float w = expf(-sp);
  int ts = t0 - WARM; if (ts < 0) ts = 0;
  float s = 0.f;
  for (int t=ts; t<t0; ++t) s = hbase[(size_t)t*Dc] + w*s;
  __syncthreads();
  if (d < TSF) {
    float m = 0.f;
    #pragma unroll
    for (int w2=0;w2<8;++w2) m += redA[w2][d];
    mag[d] = sqrtf(m);
  }
  __syncthreads();
  #pragma unroll
  for (int t=0;t<TSF;++t) {
    s = hv[t] + w * s;
    float cv = mag[t] * fabsf(s);
    hv[t] = cv;
    float s1 = cv, s2 = cv * cv;
    #pragma unroll
    for (int off=32; off; off>>=1) {
      s1 += __shfl_down(s1, off);
      s2 += __shfl_down(s2, off);
    }
    if (!lane) { redA[wv][t] = s1; redB[wv][t] = s2; }
  }
  __syncthreads();
  if (d < TSF) {
    float m1 = 0.f, m2 = 0.f;
    #pragma unroll
    for (int w2=0;w2<8;++w2) { m1 += redA[w2][d]; m2 += redB[w2][d]; }
    float mu = m1 * (1.f/Dc);
    float var = fmaxf(m2 * (1.f/Dc) - mu*mu, 0.f);
    muS[d] = mu;
    rsS[d] = rsqrtf(var + 1e-3f);
  }
  __syncthreads();
  float gv = g[l*Dc + d], bv = bt[l*Dc + d];
  unsigned short* yp = yb + ((size_t)b*Tc + t0)*Dc + d;
  #pragma unroll
  for (int t=0;t<TSF;++t)
    yp[(size_t)t*Dc] = f2bf((hv[t] - muS[t]) * rsS[t] * gv + bv);
}

template<int CH> __device__ inline int swz(int row) {
  if constexpr (CH == 8) return row & 7;
  else return (row & 3) ^ ((row >> 3) & 1);
}

// ---------- bf16 MFMA GEMM, dbuf LDS, 1 barrier/K-step, XCD supertiles ----
// EPI 0: Cb=bf16(gelu(z+bias)); 1: C+=z+bias (+ chunk partials, opt Cb);
// 2: C=z.
template<int EPI, int TM, int TN, int BK>
__global__ __launch_bounds__(256) void mgemm(
    const unsigned short* __restrict__ A,
    const unsigned short* __restrict__ Bt,
    const float* __restrict__ bias,
    float* __restrict__ C, unsigned short* __restrict__ Cb,
    float* __restrict__ part,
    int N, int K, int nrow)
{
  constexpr int CH = BK / 8;
  constexpr int PA = TM*CH/256, PB = TN*CH/256;
  constexpr int WM = TM/2, WN = TN/2;
  constexpr int AM = WM/16, AN = WN/16;
  constexpr int NKH = BK/32;
  constexpr int ASTG = TM*BK, BSTG = TN*BK;
  __shared__ unsigned short As[2*ASTG];
  __shared__ unsigned short Bs[2*BSTG];
  int tid = threadIdx.x;
  int lane = tid & 63, w = tid >> 6;
  int wr = w >> 1, wc = w & 1;
  int bid = blockIdx.x;
  int xcd = bid & 7, i = bid >> 3;
  int npx = nrow >> 3;
  int m0 = (xcd * npx + (i % npx)) * TM;
  int n0 = (i / npx) * TN;

  const unsigned short* ag[PA];
  const unsigned short* bg[PB];
  int aldst[PA], bldst[PB];
  #pragma unroll
  for (int p=0;p<PA;++p) {
    int ci = p*256 + tid;
    int row = ci / CH, cp = ci % CH;
    int cg = cp ^ swz<CH>(row);
    ag[p] = A + (size_t)(m0+row)*K + cg*8;
    aldst[p] = (p*256 + w*64)*8;
  }
  #pragma unroll
  for (int p=0;p<PB;++p) {
    int ci = p*256 + tid;
    int row = ci / CH, cp = ci % CH;
    int cg = cp ^ swz<CH>(row);
    bg[p] = Bt + (size_t)(n0+row)*K + cg*8;
    bldst[p] = (p*256 + w*64)*8;
  }

  int r = lane & 15, quad = lane >> 4;
  int aoff[NKH][AM], boff[NKH][AN];
  #pragma unroll
  for (int kh=0;kh<NKH;++kh) {
    int cb = kh*4 + quad;
    #pragma unroll
    for (int i2=0;i2<AM;++i2)
      aoff[kh][i2] = (wr*WM + i2*16 + r)*BK + ((cb ^ swz<CH>(r)) & (CH-1))*8;
    #pragma unroll
    for (int j=0;j<AN;++j)
      boff[kh][j] = (wc*WN + j*16 + r)*BK + ((cb ^ swz<CH>(r)) & (CH-1))*8;
  }

  f32x4 acc[AM][AN];
  #pragma unroll
  for (int i2=0;i2<AM;++i2)
    #pragma unroll
    for (int j=0;j<AN;++j)
      acc[i2][j] = (f32x4){0.f,0.f,0.f,0.f};

  #pragma unroll
  for (int p=0;p<PA;++p) gload_lds16(ag[p], &As[aldst[p]]);
  #pragma unroll
  for (int p=0;p<PB;++p) gload_lds16(bg[p], &Bs[bldst[p]]);

  int nk = K / BK;
  for (int ki = 0; ki < nk; ++ki) {
    __syncthreads();
    int cur = ki & 1, nxt = cur ^ 1;
    if (ki + 1 < nk) {
      int kk = (ki + 1) * BK;
      #pragma unroll
      for (int p=0;p<PA;++p) gload_lds16(ag[p] + kk, &As[nxt*ASTG + aldst[p]]);
      #pragma unroll
      for (int p=0;p<PB;++p) gload_lds16(bg[p] + kk, &Bs[nxt*BSTG + bldst[p]]);
    }
    #pragma unroll
    for (int kh=0;kh<NKH;++kh) {
      short8 af[AM], bfr[AN];
      #pragma unroll
      for (int i2=0;i2<AM;++i2) af[i2] = *(const short8*)&As[cur*ASTG + aoff[kh][i2]];
      #pragma unroll
      for (int j=0;j<AN;++j) bfr[j] = *(const short8*)&Bs[cur*BSTG + boff[kh][j]];
      #pragma unroll
      for (int i2=0;i2<AM;++i2)
        #pragma unroll
        for (int j=0;j<AN;++j)
          acc[i2][j] = __builtin_amdgcn_mfma_f32_16x16x32_bf16(af[i2], bfr[j], acc[i2][j], 0, 0, 0);
    }
  }

  #pragma unroll
  for (int i2=0;i2<AM;++i2) {
    int rowb = m0 + wr*WM + i2*16 + quad*4;
    #pragma unroll
    for (int j=0;j<AN;++j) {
      int col = n0 + wc*WN + j*16 + r;
      float bv = 0.f;
      if (EPI != 2) bv = bias[col];
      float ps = 0.f;
      #pragma unroll
      for (int reg=0;reg<4;++reg) {
        size_t idx = (size_t)(rowb + reg) * N + col;
        float z = acc[i2][j][reg] + bv;
        if (EPI == 0) {
          Cb[idx] = f2bf(gelu_f(z));
        } else if (EPI == 1) {
          float hv = C[idx] + z;
          C[idx] = hv;
          ps += hv;
          if (Cb) Cb[idx] = f2bf(hv);
        } else {
          C[idx] = z;
        }
      }
      if (EPI == 1 && part) {
        ps += __shfl_xor(ps, 16);
        ps += __shfl_xor(ps, 32);
        if (quad == 0) {
          int chunk = (m0 + wr*WM + i2*16) >> 4;   // TSF=16
          part[(size_t)chunk * N + col] = ps;
        }
      }
    }
  }
}

extern "C" void kernel_launch(void* const* d_in, const int* in_sizes, int n_in,
                              void* d_out, int out_size, void* d_ws, size_t ws_size,
                              hipStream_t stream) {
  const int*   x     = (const int*)  d_in[0];
  const float* embed = (const float*)d_in[1];
  const float* kvec  = (const float*)d_in[2];
  const float* g     = (const float*)d_in[3];
  const float* bt    = (const float*)d_in[4];
  const float* W1    = (const float*)d_in[5];
  const float* b1    = (const float*)d_in[6];
  const float* W2    = (const float*)d_in[7];
  const float* b2    = (const float*)d_in[8];
  float* out = (float*)d_out;

  const size_t NTD = (size_t)Bc * Tc * Dc;   // 4,194,304
  const size_t NTH = (size_t)Bc * Tc * Hc;   // 16,777,216
  char* wsb = (char*)d_ws;
  float* h      = (float*)wsb;                wsb += NTD*4;               // 16MB
  float* tmpA   = (float*)wsb;                wsb += NTD*4;               // 16MB (th)
  float* partA  = (float*)wsb;                wsb += (size_t)Bc*NCF*Dc*4; // 1MB
  float* partB  = (float*)wsb;                wsb += (size_t)Bc*NCF*Dc*4; // 1MB
  unsigned short* yb   = (unsigned short*)wsb; wsb += NTD*2;              // 8MB
  unsigned short* a1b  = (unsigned short*)wsb; wsb += NTH*2;              // 32MB
  unsigned short* hb   = (unsigned short*)wsb; wsb += NTD*2;              // 8MB
  unsigned short* W1t  = (unsigned short*)wsb; wsb += (size_t)3*Dc*Hc*2;  // 6MB
  unsigned short* W2t  = (unsigned short*)wsb; wsb += (size_t)3*Dc*Hc*2;  // 6MB
  unsigned short* emb  = (unsigned short*)wsb; wsb += (size_t)Vc*Dc*2;

  // merged weight prep (1 dispatch)
  wprep<<<dim3(6144 + (Vc*Dc+255)/256), 256, 0, stream>>>(
      W1, W1t, W2, W2t, embed, emb);

  // prologue: embed+cumprod+tanh+chunk-sums; bd_apply inlines the prefix
  embed_part<<<dim3(NCF, Bc), 1024, 0, stream>>>(x, embed, tmpA, partA);
  bd_apply<<<dim3(NCF, Bc), 512, 0, stream>>>(tmpA, partA, x, embed, h, partB);

  for (int l = 0; l < 3; ++l) {
    mag_scan_ln<<<dim3(NCF, Bc), 512, 0, stream>>>(h, partB, kvec, l, g, bt, yb);
    // z = gelu(y @ W1 + b1): M=8192 N=2048 K=512; 64x64 BK=64 -> 4096 blocks
    mgemm<0,64,64,64><<<dim3(128*(Hc/64)), 256, 0, stream>>>(
        yb, W1t + (size_t)l*Hc*Dc, b1 + (size_t)l*Hc, nullptr, a1b, nullptr,
        Hc, Dc, 128);
    // h += z @ W2 + b2 (+ h chunk partials): 64x64 tile, BK=64 -> 1024 blocks
    mgemm<1,64,64,64><<<dim3(128*(Dc/64)), 256, 0, stream>>>(
        a1b, W2t + (size_t)l*Dc*Hc, b2 + (size_t)l*Dc, h,
        (l == 2) ? hb : nullptr, (l < 2) ? partB : nullptr, Dc, Hc, 128);
  }
  // out = h @ embed^T: M=8192 N=256 K=512; 64x64 tiles, nrow=128
  mgemm<2,64,64,32><<<dim3(128*(Vc/64)), 256, 0, stream>>>(
      hb, emb, nullptr, out, nullptr, nullptr, Vc, Dc, 128);
}

// Round 14
// 406.954 us; speedup vs baseline: 3.1478x; 1.0405x over previous
//
#include <hip/hip_runtime.h>
#include <math.h>

// DeltaLM: B=4 T=2048 D=512 H=2048 L=3 V=256
// decay einsum == geometric scan S[i]=h[i]+w*S[i-1], w=exp(-softplus(k)).
// Round 14: exact revert to R11 (measured best, 408us). R13's inline
// chunk_prefix regressed (+15us: blocks with c>=64 serialize up to 127
// strided loads on the critical path; separate wave-parallel part_prefix
// dispatches are cheaper). R12's cooperative grid.sync cost ~600us/launch.
// GEMMs at m97-structure plateau (R8 occupancy / R9 L2 / R10 LDS-pipe all
// falsified); elementwise within ~2x of latency floor.

constexpr int Bc = 4, Tc = 2048, Dc = 512, Hc = 2048, Vc = 256;
constexpr int TSF = 16, NCF = 128, WARM = 20;  // fine time chunks: 128 x 16

typedef __attribute__((ext_vector_type(8))) short short8;
typedef __attribute__((ext_vector_type(4))) float f32x4;

__device__ inline unsigned short f2bf(float f) {  // RNE fp32->bf16
  unsigned int u = __float_as_uint(f);
  u += 0x7fffu + ((u >> 16) & 1u);
  return (unsigned short)(u >> 16);
}

__device__ inline void gload_lds16(const void* g, void* l) {
  __builtin_amdgcn_global_load_lds(
      (const __attribute__((address_space(1))) void*)g,
      (__attribute__((address_space(3))) void*)l, 16, 0, 0);
}

// gelu(z) = 0.5 z (1+erf(z/sqrt2)); erf via A&S 7.1.26, |eps|<=1.5e-7
__device__ inline float gelu_f(float z) {
  float x = z * 0.707106781186547524f;
  float ax = fabsf(x);
  float t = 1.0f / (1.0f + 0.3275911f * ax);
  float poly = t*(0.254829592f + t*(-0.284496736f + t*(1.421413741f +
               t*(-1.453152027f + t*1.061405429f))));
  float er = 1.0f - poly * __expf(-ax*ax);
  er = copysignf(er, x);
  return 0.5f * z * (1.0f + er);
}

// ---------- merged weight prep: W1t, W2t (transpose->bf16) + emb ----------
__device__ inline void tr32(const float* Wl, unsigned short* Wtl,
                            int R, int C, int c0, int r0, int tid,
                            float (*tile)[33]) {
  int tx = tid & 31, ty = tid >> 5;
  for (int i = ty; i < 32; i += 8)
    tile[i][tx] = Wl[(size_t)(r0+i)*C + (c0+tx)];
  __syncthreads();
  for (int i = ty; i < 32; i += 8)
    Wtl[(size_t)(c0+i)*R + (r0+tx)] = f2bf(tile[tx][i]);
}

__global__ __launch_bounds__(256) void wprep(
    const float* __restrict__ W1, unsigned short* __restrict__ W1t,
    const float* __restrict__ W2, unsigned short* __restrict__ W2t,
    const float* __restrict__ embed, unsigned short* __restrict__ emb)
{
  __shared__ float tile[32][33];
  int bid = blockIdx.x, tid = threadIdx.x;
  if (bid < 3072) {            // W1: (L, Dc, Hc) -> (L, Hc, Dc) bf16
    int l = bid >> 10, rem = bid & 1023;
    int cx = rem & 63, ry = rem >> 6;      // C/32=64, R/32=16
    tr32(W1 + (size_t)l*Dc*Hc, W1t + (size_t)l*Dc*Hc, Dc, Hc,
         cx*32, ry*32, tid, tile);
  } else if (bid < 6144) {     // W2: (L, Hc, Dc) -> (L, Dc, Hc) bf16
    int b2 = bid - 3072;
    int l = b2 >> 10, rem = b2 & 1023;
    int cx = rem & 15, ry = rem >> 4;      // C/32=16, R/32=64
    tr32(W2 + (size_t)l*Hc*Dc, W2t + (size_t)l*Hc*Dc, Hc, Dc,
         cx*32, ry*32, tid, tile);
  } else {                     // emb: fp32 -> bf16
    int i = (bid - 6144)*256 + tid;
    if (i < Vc*Dc) emb[i] = f2bf(embed[i]);
  }
}

// ---------- embed gather + cumprod + tanh + chunk sums (fused) ----------
// block = one chunk (16 tokens), 16 waves; wave w owns token c*16+w.
// phase 2 re-reads the L2-hot th written in phase 1 to form partA.
__global__ __launch_bounds__(1024) void embed_part(
    const int* __restrict__ x, const float* __restrict__ embed,
    float* __restrict__ th, float* __restrict__ partA)
{
  int c = blockIdx.x, b = blockIdx.y;
  int wv = threadIdx.x >> 6, lane = threadIdx.x & 63;
  int token = b*Tc + c*TSF + wv;
  int row = x[token];
  const float* e = embed + (size_t)row * Dc + lane * 8;
  float v[8];
  {
    float4 a = *(const float4*)e;
    float4 bb = *(const float4*)(e + 4);
    v[0]=a.x; v[1]=a.y; v[2]=a.z; v[3]=a.w;
    v[4]=bb.x; v[5]=bb.y; v[6]=bb.z; v[7]=bb.w;
  }
  float p = v[0];
  #pragma unroll
  for (int j=1;j<8;++j) p *= v[j];
  float incl = p;
  #pragma unroll
  for (int off=1; off<64; off<<=1) {
    float t = __shfl_up(incl, off);
    if (lane >= off) incl *= t;
  }
  float excl = __shfl_up(incl, 1);
  if (lane == 0) excl = 1.0f;
  float cc = excl;
  float o[8];
  #pragma unroll
  for (int j=0;j<8;++j) { cc *= v[j]; o[j] = tanhf(cc); }
  float* dst = th + (size_t)token * Dc + lane * 8;
  *(float4*)dst     = make_float4(o[0],o[1],o[2],o[3]);
  *(float4*)(dst+4) = make_float4(o[4],o[5],o[6],o[7]);
  __syncthreads();
  int d = threadIdx.x;
  if (d < Dc) {
    const float* pp = th + ((size_t)b*Tc + c*TSF)*Dc + d;
    float s = 0.f;
    #pragma unroll
    for (int t=0;t<TSF;++t) s += pp[(size_t)t*Dc];
    partA[((size_t)b*NCF + c)*Dc + d] = s;
  }
}

// ---------- in-place exclusive prefix over 128 chunks: 1 wave per (b,d) ---
__global__ __launch_bounds__(512) void part_prefix(float* __restrict__ part)
{
  int pair = blockIdx.x * 8 + (threadIdx.x >> 6);   // 2048 (b,d) pairs
  int lane = threadIdx.x & 63;
  int b = pair >> 9, d = pair & 511;
  size_t i0 = ((size_t)b*NCF + 2*lane)*Dc + d;
  float v0 = part[i0];
  float v1 = part[i0 + Dc];
  float ps = v0 + v1;
  float incl = ps;
  #pragma unroll
  for (int off=1; off<64; off<<=1) {
    float t = __shfl_up(incl, off);
    if (lane >= off) incl += t;
  }
  float excl = incl - ps;
  part[i0]      = excl;
  part[i0 + Dc] = excl + v0;
}

// ---------- bd = cumsum_t(th); h = embed[x]*(1+bd); writes h chunk sum ----
__global__ __launch_bounds__(512) void bd_apply(
    const float* __restrict__ th, const float* __restrict__ partA,
    const int* __restrict__ x, const float* __restrict__ embed,
    float* __restrict__ h, float* __restrict__ partB)
{
  int c = blockIdx.x, b = blockIdx.y, d = threadIdx.x;
  float acc = partA[((size_t)b*NCF + c)*Dc + d];   // exclusive prefix (th)
  float hsum = 0.f;
  #pragma unroll
  for (int t=0;t<TSF;++t) {
    int tt = c*TSF + t;
    size_t idx = ((size_t)b*Tc + tt)*Dc + d;
    acc += th[idx];
    int row = x[b*Tc + tt];
    float e = embed[(size_t)row*Dc + d];
    float hv = e * (1.0f + acc);
    h[idx] = hv;
    hsum += hv;
  }
  partB[((size_t)b*NCF + c)*Dc + d] = hsum;        // raw chunk sum (h)
}

// ---------- fused: mag (LDS only) + geometric scan + LayerNorm -> bf16 ----
__global__ __launch_bounds__(512) void mag_scan_ln(
    const float* __restrict__ h, const float* __restrict__ part,
    const float* __restrict__ kvec, int l,
    const float* __restrict__ g, const float* __restrict__ bt,
    unsigned short* __restrict__ yb)
{
  __shared__ float redA[8][TSF];
  __shared__ float redB[8][TSF];
  __shared__ float mag[TSF], muS[TSF], rsS[TSF];
  int c = blockIdx.x, b = blockIdx.y, d = threadIdx.x;
  int lane = d & 63, wv = d >> 6;
  float acc = part[((size_t)b*NCF + c)*Dc + d];    // exclusive prefix (h)
  int t0 = c * TSF;
  const float* hbase = h + (size_t)b*Tc*Dc + d;
  float hp = (t0 > 0) ? hbase[(size_t)(t0-1)*Dc] : 0.f;
  float hv[TSF];
  #pragma unroll
  for (int t=0;t<TSF;++t) {
    hv[t] = hbase[(size_t)(t0+t)*Dc];
    acc += hv[t];
    float diff = acc - hp;
    hp = hv[t];
    float s = diff * diff;
    #pragma unroll
    for (int off=32; off; off>>=1) s += __shfl_down(s, off);
    if (!lane) redA[wv][t] = s;
  }
  float kk = kvec[l];
  float sp = kk > 0.f ? kk + log1pf(expf(-kk)) : log1pf(expf(kk));
  float w = expf(-sp);
  int ts = t0 - WARM; if (ts < 0) ts = 0;
  float s = 0.f;
  for (int t=ts; t<t0; ++t) s = hbase[(size_t)t*Dc] + w*s;
  __syncthreads();
  if (d < TSF) {
    float m = 0.f;
    #pragma unroll
    for (int w2=0;w2<8;++w2) m += redA[w2][d];
    mag[d] = sqrtf(m);
  }
  __syncthreads();
  #pragma unroll
  for (int t=0;t<TSF;++t) {
    s = hv[t] + w * s;
    float cv = mag[t] * fabsf(s);
    hv[t] = cv;
    float s1 = cv, s2 = cv * cv;
    #pragma unroll
    for (int off=32; off; off>>=1) {
      s1 += __shfl_down(s1, off);
      s2 += __shfl_down(s2, off);
    }
    if (!lane) { redA[wv][t] = s1; redB[wv][t] = s2; }
  }
  __syncthreads();
  if (d < TSF) {
    float m1 = 0.f, m2 = 0.f;
    #pragma unroll
    for (int w2=0;w2<8;++w2) { m1 += redA[w2][d]; m2 += redB[w2][d]; }
    float mu = m1 * (1.f/Dc);
    float var = fmaxf(m2 * (1.f/Dc) - mu*mu, 0.f);
    muS[d] = mu;
    rsS[d] = rsqrtf(var + 1e-3f);
  }
  __syncthreads();
  float gv = g[l*Dc + d], bv = bt[l*Dc + d];
  unsigned short* yp = yb + ((size_t)b*Tc + t0)*Dc + d;
  #pragma unroll
  for (int t=0;t<TSF;++t)
    yp[(size_t)t*Dc] = f2bf((hv[t] - muS[t]) * rsS[t] * gv + bv);
}

template<int CH> __device__ inline int swz(int row) {
  if constexpr (CH == 8) return row & 7;
  else return (row & 3) ^ ((row >> 3) & 1);
}

// ---------- bf16 MFMA GEMM, dbuf LDS, 1 barrier/K-step, XCD supertiles ----
// A: MxK bf16 row-major. Bt: NxK bf16 row-major. C = A @ Bt^T.
// 1D grid; XCD x = bid&7 owns an M-panel x all N (operands L2-resident).
// EPI 0: Cb=bf16(gelu(z+bias)); 1: C+=z+bias (+ chunk partials, opt Cb);
// 2: C=z.
template<int EPI, int TM, int TN, int BK>
__global__ __launch_bounds__(256) void mgemm(
    const unsigned short* __restrict__ A,
    const unsigned short* __restrict__ Bt,
    const float* __restrict__ bias,
    float* __restrict__ C, unsigned short* __restrict__ Cb,
    float* __restrict__ part,
    int N, int K, int nrow)
{
  constexpr int CH = BK / 8;
  constexpr int PA = TM*CH/256, PB = TN*CH/256;
  constexpr int WM = TM/2, WN = TN/2;
  constexpr int AM = WM/16, AN = WN/16;
  constexpr int NKH = BK/32;
  constexpr int ASTG = TM*BK, BSTG = TN*BK;
  __shared__ unsigned short As[2*ASTG];
  __shared__ unsigned short Bs[2*BSTG];
  int tid = threadIdx.x;
  int lane = tid & 63, w = tid >> 6;
  int wr = w >> 1, wc = w & 1;
  int bid = blockIdx.x;
  int xcd = bid & 7, i = bid >> 3;
  int npx = nrow >> 3;
  int m0 = (xcd * npx + (i % npx)) * TM;
  int n0 = (i / npx) * TN;

  const unsigned short* ag[PA];
  const unsigned short* bg[PB];
  int aldst[PA], bldst[PB];
  #pragma unroll
  for (int p=0;p<PA;++p) {
    int ci = p*256 + tid;
    int row = ci / CH, cp = ci % CH;
    int cg = cp ^ swz<CH>(row);
    ag[p] = A + (size_t)(m0+row)*K + cg*8;
    aldst[p] = (p*256 + w*64)*8;
  }
  #pragma unroll
  for (int p=0;p<PB;++p) {
    int ci = p*256 + tid;
    int row = ci / CH, cp = ci % CH;
    int cg = cp ^ swz<CH>(row);
    bg[p] = Bt + (size_t)(n0+row)*K + cg*8;
    bldst[p] = (p*256 + w*64)*8;
  }

  int r = lane & 15, quad = lane >> 4;
  int aoff[NKH][AM], boff[NKH][AN];
  #pragma unroll
  for (int kh=0;kh<NKH;++kh) {
    int cb = kh*4 + quad;
    #pragma unroll
    for (int i2=0;i2<AM;++i2)
      aoff[kh][i2] = (wr*WM + i2*16 + r)*BK + ((cb ^ swz<CH>(r)) & (CH-1))*8;
    #pragma unroll
    for (int j=0;j<AN;++j)
      boff[kh][j] = (wc*WN + j*16 + r)*BK + ((cb ^ swz<CH>(r)) & (CH-1))*8;
  }

  f32x4 acc[AM][AN];
  #pragma unroll
  for (int i2=0;i2<AM;++i2)
    #pragma unroll
    for (int j=0;j<AN;++j)
      acc[i2][j] = (f32x4){0.f,0.f,0.f,0.f};

  #pragma unroll
  for (int p=0;p<PA;++p) gload_lds16(ag[p], &As[aldst[p]]);
  #pragma unroll
  for (int p=0;p<PB;++p) gload_lds16(bg[p], &Bs[bldst[p]]);

  int nk = K / BK;
  for (int ki = 0; ki < nk; ++ki) {
    __syncthreads();
    int cur = ki & 1, nxt = cur ^ 1;
    if (ki + 1 < nk) {
      int kk = (ki + 1) * BK;
      #pragma unroll
      for (int p=0;p<PA;++p) gload_lds16(ag[p] + kk, &As[nxt*ASTG + aldst[p]]);
      #pragma unroll
      for (int p=0;p<PB;++p) gload_lds16(bg[p] + kk, &Bs[nxt*BSTG + bldst[p]]);
    }
    #pragma unroll
    for (int kh=0;kh<NKH;++kh) {
      short8 af[AM], bfr[AN];
      #pragma unroll
      for (int i2=0;i2<AM;++i2) af[i2] = *(const short8*)&As[cur*ASTG + aoff[kh][i2]];
      #pragma unroll
      for (int j=0;j<AN;++j) bfr[j] = *(const short8*)&Bs[cur*BSTG + boff[kh][j]];
      #pragma unroll
      for (int i2=0;i2<AM;++i2)
        #pragma unroll
        for (int j=0;j<AN;++j)
          acc[i2][j] = __builtin_amdgcn_mfma_f32_16x16x32_bf16(af[i2], bfr[j], acc[i2][j], 0, 0, 0);
    }
  }

  #pragma unroll
  for (int i2=0;i2<AM;++i2) {
    int rowb = m0 + wr*WM + i2*16 + quad*4;
    #pragma unroll
    for (int j=0;j<AN;++j) {
      int col = n0 + wc*WN + j*16 + r;
      float bv = 0.f;
      if (EPI != 2) bv = bias[col];
      float ps = 0.f;
      #pragma unroll
      for (int reg=0;reg<4;++reg) {
        size_t idx = (size_t)(rowb + reg) * N + col;
        float z = acc[i2][j][reg] + bv;
        if (EPI == 0) {
          Cb[idx] = f2bf(gelu_f(z));
        } else if (EPI == 1) {
          float hv = C[idx] + z;
          C[idx] = hv;
          ps += hv;
          if (Cb) Cb[idx] = f2bf(hv);
        } else {
          C[idx] = z;
        }
      }
      if (EPI == 1 && part) {
        ps += __shfl_xor(ps, 16);
        ps += __shfl_xor(ps, 32);
        if (quad == 0) {
          int chunk = (m0 + wr*WM + i2*16) >> 4;   // TSF=16
          part[(size_t)chunk * N + col] = ps;
        }
      }
    }
  }
}

extern "C" void kernel_launch(void* const* d_in, const int* in_sizes, int n_in,
                              void* d_out, int out_size, void* d_ws, size_t ws_size,
                              hipStream_t stream) {
  const int*   x     = (const int*)  d_in[0];
  const float* embed = (const float*)d_in[1];
  const float* kvec  = (const float*)d_in[2];
  const float* g     = (const float*)d_in[3];
  const float* bt    = (const float*)d_in[4];
  const float* W1    = (const float*)d_in[5];
  const float* b1    = (const float*)d_in[6];
  const float* W2    = (const float*)d_in[7];
  const float* b2    = (const float*)d_in[8];
  float* out = (float*)d_out;

  const size_t NTD = (size_t)Bc * Tc * Dc;   // 4,194,304
  const size_t NTH = (size_t)Bc * Tc * Hc;   // 16,777,216
  char* wsb = (char*)d_ws;
  float* h      = (float*)wsb;                wsb += NTD*4;               // 16MB
  float* tmpA   = (float*)wsb;                wsb += NTD*4;               // 16MB (th)
  float* partA  = (float*)wsb;                wsb += (size_t)Bc*NCF*Dc*4; // 1MB
  float* partB  = (float*)wsb;                wsb += (size_t)Bc*NCF*Dc*4; // 1MB
  unsigned short* yb   = (unsigned short*)wsb; wsb += NTD*2;              // 8MB
  unsigned short* a1b  = (unsigned short*)wsb; wsb += NTH*2;              // 32MB
  unsigned short* hb   = (unsigned short*)wsb; wsb += NTD*2;              // 8MB
  unsigned short* W1t  = (unsigned short*)wsb; wsb += (size_t)3*Dc*Hc*2;  // 6MB
  unsigned short* W2t  = (unsigned short*)wsb; wsb += (size_t)3*Dc*Hc*2;  // 6MB
  unsigned short* emb  = (unsigned short*)wsb; wsb += (size_t)Vc*Dc*2;

  // merged weight prep (1 dispatch)
  wprep<<<dim3(6144 + (Vc*Dc+255)/256), 256, 0, stream>>>(
      W1, W1t, W2, W2t, embed, emb);

  // prologue: embed+cumprod+tanh+chunk-sums fused (1 dispatch)
  embed_part<<<dim3(NCF, Bc), 1024, 0, stream>>>(x, embed, tmpA, partA);
  part_prefix<<<dim3(256), 512, 0, stream>>>(partA);
  bd_apply<<<dim3(NCF, Bc), 512, 0, stream>>>(tmpA, partA, x, embed, h, partB);
  part_prefix<<<dim3(256), 512, 0, stream>>>(partB);

  for (int l = 0; l < 3; ++l) {
    mag_scan_ln<<<dim3(NCF, Bc), 512, 0, stream>>>(h, partB, kvec, l, g, bt, yb);
    // z = gelu(y @ W1 + b1): M=8192 N=2048 K=512; 64x64 BK=64 -> 4096 blocks
    mgemm<0,64,64,64><<<dim3(128*(Hc/64)), 256, 0, stream>>>(
        yb, W1t + (size_t)l*Hc*Dc, b1 + (size_t)l*Hc, nullptr, a1b, nullptr,
        Hc, Dc, 128);
    // h += z @ W2 + b2 (+ h chunk partials): 64x64 tile, BK=64 -> 1024 blocks
    mgemm<1,64,64,64><<<dim3(128*(Dc/64)), 256, 0, stream>>>(
        a1b, W2t + (size_t)l*Dc*Hc, b2 + (size_t)l*Dc, h,
        (l == 2) ? hb : nullptr, (l < 2) ? partB : nullptr, Dc, Hc, 128);
    if (l < 2) part_prefix<<<dim3(256), 512, 0, stream>>>(partB);
  }
  // out = h @ embed^T: M=8192 N=256 K=512; 64x64 tiles, nrow=128
  mgemm<2,64,64,32><<<dim3(128*(Vc/64)), 256, 0, stream>>>(
      hb, emb, nullptr, out, nullptr, nullptr, Vc, Dc, 128);
}

// Round 16
// 401.999 us; speedup vs baseline: 3.1866x; 1.0123x over previous
//
#include <hip/hip_runtime.h>
#include <math.h>

// DeltaLM: B=4 T=2048 D=512 H=2048 L=3 V=256
// decay einsum == geometric scan S[i]=h[i]+w*S[i-1], w=exp(-softplus(k)).
// Round 16: R15 had a factor-of-w bug (seed s=w*partW then loop applied
// another w -> S off by w everywhere, absmax 0.48). Fix: seed s=partW[c-1];
// the recurrence loop supplies the w. partW[c-1]=S_local(chunk end), trunc
// error w^16 ~ 7.6e-10 (better than the old 20-step warmup).

constexpr int Bc = 4, Tc = 2048, Dc = 512, Hc = 2048, Vc = 256;
constexpr int TSF = 16, NCF = 128;

typedef __attribute__((ext_vector_type(8))) short short8;
typedef __attribute__((ext_vector_type(4))) float f32x4;

__device__ inline unsigned short f2bf(float f) {  // RNE fp32->bf16
  unsigned int u = __float_as_uint(f);
  u += 0x7fffu + ((u >> 16) & 1u);
  return (unsigned short)(u >> 16);
}

__device__ inline void gload_lds16(const void* g, void* l) {
  __builtin_amdgcn_global_load_lds(
      (const __attribute__((address_space(1))) void*)g,
      (__attribute__((address_space(3))) void*)l, 16, 0, 0);
}

// gelu(z) = 0.5 z (1+erf(z/sqrt2)); erf via A&S 7.1.26, |eps|<=1.5e-7
__device__ inline float gelu_f(float z) {
  float x = z * 0.707106781186547524f;
  float ax = fabsf(x);
  float t = 1.0f / (1.0f + 0.3275911f * ax);
  float poly = t*(0.254829592f + t*(-0.284496736f + t*(1.421413741f +
               t*(-1.453152027f + t*1.061405429f))));
  float er = 1.0f - poly * __expf(-ax*ax);
  er = copysignf(er, x);
  return 0.5f * z * (1.0f + er);
}

__device__ inline float decay_w(const float* kvec, int l) {
  float kk = kvec[l];
  float sp = kk > 0.f ? kk + log1pf(expf(-kk)) : log1pf(expf(kk));
  return expf(-sp);
}

// ---------- merged weight prep: W1t, W2t (transpose->bf16) + emb ----------
__device__ inline void tr32(const float* Wl, unsigned short* Wtl,
                            int R, int C, int c0, int r0, int tid,
                            float (*tile)[33]) {
  int tx = tid & 31, ty = tid >> 5;
  for (int i = ty; i < 32; i += 8)
    tile[i][tx] = Wl[(size_t)(r0+i)*C + (c0+tx)];
  __syncthreads();
  for (int i = ty; i < 32; i += 8)
    Wtl[(size_t)(c0+i)*R + (r0+tx)] = f2bf(tile[tx][i]);
}

__global__ __launch_bounds__(256) void wprep(
    const float* __restrict__ W1, unsigned short* __restrict__ W1t,
    const float* __restrict__ W2, unsigned short* __restrict__ W2t,
    const float* __restrict__ embed, unsigned short* __restrict__ emb)
{
  __shared__ float tile[32][33];
  int bid = blockIdx.x, tid = threadIdx.x;
  if (bid < 3072) {            // W1: (L, Dc, Hc) -> (L, Hc, Dc) bf16
    int l = bid >> 10, rem = bid & 1023;
    int cx = rem & 63, ry = rem >> 6;      // C/32=64, R/32=16
    tr32(W1 + (size_t)l*Dc*Hc, W1t + (size_t)l*Dc*Hc, Dc, Hc,
         cx*32, ry*32, tid, tile);
  } else if (bid < 6144) {     // W2: (L, Hc, Dc) -> (L, Dc, Hc) bf16
    int b2 = bid - 3072;
    int l = b2 >> 10, rem = b2 & 1023;
    int cx = rem & 15, ry = rem >> 4;      // C/32=16, R/32=64
    tr32(W2 + (size_t)l*Hc*Dc, W2t + (size_t)l*Hc*Dc, Hc, Dc,
         cx*32, ry*32, tid, tile);
  } else {                     // emb: fp32 -> bf16
    int i = (bid - 6144)*256 + tid;
    if (i < Vc*Dc) emb[i] = f2bf(embed[i]);
  }
}

// ---------- embed gather + cumprod + tanh + chunk sums (fused) ----------
__global__ __launch_bounds__(1024) void embed_part(
    const int* __restrict__ x, const float* __restrict__ embed,
    float* __restrict__ th, float* __restrict__ partA)
{
  int c = blockIdx.x, b = blockIdx.y;
  int wv = threadIdx.x >> 6, lane = threadIdx.x & 63;
  int token = b*Tc + c*TSF + wv;
  int row = x[token];
  const float* e = embed + (size_t)row * Dc + lane * 8;
  float v[8];
  {
    float4 a = *(const float4*)e;
    float4 bb = *(const float4*)(e + 4);
    v[0]=a.x; v[1]=a.y; v[2]=a.z; v[3]=a.w;
    v[4]=bb.x; v[5]=bb.y; v[6]=bb.z; v[7]=bb.w;
  }
  float p = v[0];
  #pragma unroll
  for (int j=1;j<8;++j) p *= v[j];
  float incl = p;
  #pragma unroll
  for (int off=1; off<64; off<<=1) {
    float t = __shfl_up(incl, off);
    if (lane >= off) incl *= t;
  }
  float excl = __shfl_up(incl, 1);
  if (lane == 0) excl = 1.0f;
  float cc = excl;
  float o[8];
  #pragma unroll
  for (int j=0;j<8;++j) { cc *= v[j]; o[j] = tanhf(cc); }
  float* dst = th + (size_t)token * Dc + lane * 8;
  *(float4*)dst     = make_float4(o[0],o[1],o[2],o[3]);
  *(float4*)(dst+4) = make_float4(o[4],o[5],o[6],o[7]);
  __syncthreads();
  int d = threadIdx.x;
  if (d < Dc) {
    const float* pp = th + ((size_t)b*Tc + c*TSF)*Dc + d;
    float s = 0.f;
    #pragma unroll
    for (int t=0;t<TSF;++t) s += pp[(size_t)t*Dc];
    partA[((size_t)b*NCF + c)*Dc + d] = s;
  }
}

// ---------- in-place exclusive prefix over 128 chunks: 1 wave per (b,d) ---
__global__ __launch_bounds__(512) void part_prefix(float* __restrict__ part)
{
  int pair = blockIdx.x * 8 + (threadIdx.x >> 6);   // 2048 (b,d) pairs
  int lane = threadIdx.x & 63;
  int b = pair >> 9, d = pair & 511;
  size_t i0 = ((size_t)b*NCF + 2*lane)*Dc + d;
  float v0 = part[i0];
  float v1 = part[i0 + Dc];
  float ps = v0 + v1;
  float incl = ps;
  #pragma unroll
  for (int off=1; off<64; off<<=1) {
    float t = __shfl_up(incl, off);
    if (lane >= off) incl += t;
  }
  float excl = incl - ps;
  part[i0]      = excl;
  part[i0 + Dc] = excl + v0;
}

// ---------- bd = cumsum_t(th); h = embed[x]*(1+bd); chunk sums + weighted -
__global__ __launch_bounds__(512) void bd_apply(
    const float* __restrict__ th, const float* __restrict__ partA,
    const int* __restrict__ x, const float* __restrict__ embed,
    float* __restrict__ h, float* __restrict__ partB,
    float* __restrict__ partW, const float* __restrict__ kvec)
{
  int c = blockIdx.x, b = blockIdx.y, d = threadIdx.x;
  float w0 = decay_w(kvec, 0);
  float acc = partA[((size_t)b*NCF + c)*Dc + d];   // exclusive prefix (th)
  float hsum = 0.f, psW = 0.f;
  #pragma unroll
  for (int t=0;t<TSF;++t) {
    int tt = c*TSF + t;
    size_t idx = ((size_t)b*Tc + tt)*Dc + d;
    acc += th[idx];
    int row = x[b*Tc + tt];
    float e = embed[(size_t)row*Dc + d];
    float hv = e * (1.0f + acc);
    h[idx] = hv;
    hsum += hv;
    psW = psW * w0 + hv;                           // Horner: sum w^(15-t) hv
  }
  partB[((size_t)b*NCF + c)*Dc + d] = hsum;        // raw chunk sum (h)
  partW[((size_t)b*NCF + c)*Dc + d] = psW;         // weighted (layer-0 w)
}

// ---------- fused: mag (LDS only) + geometric scan + LayerNorm -> bf16 ----
// scan-in state: S(c*16-1) ~= partW[c-1] (truncation w^16 ~ 7.6e-10);
// the recurrence loop applies the w factor.
__global__ __launch_bounds__(512) void mag_scan_ln(
    const float* __restrict__ h, const float* __restrict__ part,
    const float* __restrict__ partW,
    const float* __restrict__ kvec, int l,
    const float* __restrict__ g, const float* __restrict__ bt,
    unsigned short* __restrict__ yb)
{
  __shared__ float redA[8][TSF];
  __shared__ float redB[8][TSF];
  __shared__ float mag[TSF], muS[TSF], rsS[TSF];
  int c = blockIdx.x, b = blockIdx.y, d = threadIdx.x;
  int lane = d & 63, wv = d >> 6;
  float acc = part[((size_t)b*NCF + c)*Dc + d];    // exclusive prefix (h)
  int t0 = c * TSF;
  const float* hbase = h + (size_t)b*Tc*Dc + d;
  float hp = (t0 > 0) ? hbase[(size_t)(t0-1)*Dc] : 0.f;
  float hv[TSF];
  #pragma unroll
  for (int t=0;t<TSF;++t) {
    hv[t] = hbase[(size_t)(t0+t)*Dc];
    acc += hv[t];
    float diff = acc - hp;
    hp = hv[t];
    float s = diff * diff;
    #pragma unroll
    for (int off=32; off; off>>=1) s += __shfl_down(s, off);
    if (!lane) redA[wv][t] = s;
  }
  float w = decay_w(kvec, l);
  // FIX(R16): seed is partW[c-1] itself; loop multiplies by w.
  float s = (c > 0) ? partW[((size_t)b*NCF + (c-1))*Dc + d] : 0.f;
  __syncthreads();
  if (d < TSF) {
    float m = 0.f;
    #pragma unroll
    for (int w2=0;w2<8;++w2) m += redA[w2][d];
    mag[d] = sqrtf(m);
  }
  __syncthreads();
  #pragma unroll
  for (int t=0;t<TSF;++t) {
    s = hv[t] + w * s;
    float cv = mag[t] * fabsf(s);
    hv[t] = cv;
    float s1 = cv, s2 = cv * cv;
    #pragma unroll
    for (int off=32; off; off>>=1) {
      s1 += __shfl_down(s1, off);
      s2 += __shfl_down(s2, off);
    }
    if (!lane) { redA[wv][t] = s1; redB[wv][t] = s2; }
  }
  __syncthreads();
  if (d < TSF) {
    float m1 = 0.f, m2 = 0.f;
    #pragma unroll
    for (int w2=0;w2<8;++w2) { m1 += redA[w2][d]; m2 += redB[w2][d]; }
    float mu = m1 * (1.f/Dc);
    float var = fmaxf(m2 * (1.f/Dc) - mu*mu, 0.f);
    muS[d] = mu;
    rsS[d] = rsqrtf(var + 1e-3f);
  }
  __syncthreads();
  float gv = g[l*Dc + d], bv = bt[l*Dc + d];
  unsigned short* yp = yb + ((size_t)b*Tc + t0)*Dc + d;
  #pragma unroll
  for (int t=0;t<TSF;++t)
    yp[(size_t)t*Dc] = f2bf((hv[t] - muS[t]) * rsS[t] * gv + bv);
}

template<int CH> __device__ inline int swz(int row) {
  if constexpr (CH == 8) return row & 7;
  else return (row & 3) ^ ((row >> 3) & 1);
}

// ---------- bf16 MFMA GEMM, dbuf LDS, 1 barrier/K-step, XCD supertiles ----
// EPI 0: Cb=bf16(gelu(z+bias)); 1: C+=z+bias (+ raw and weighted chunk
// partials via butterfly, opt Cb); 2: C=z.
template<int EPI, int TM, int TN, int BK>
__global__ __launch_bounds__(256) void mgemm(
    const unsigned short* __restrict__ A,
    const unsigned short* __restrict__ Bt,
    const float* __restrict__ bias,
    float* __restrict__ C, unsigned short* __restrict__ Cb,
    float* __restrict__ part, float* __restrict__ partW,
    const float* __restrict__ kvec, int wl,
    int N, int K, int nrow)
{
  constexpr int CH = BK / 8;
  constexpr int PA = TM*CH/256, PB = TN*CH/256;
  constexpr int WM = TM/2, WN = TN/2;
  constexpr int AM = WM/16, AN = WN/16;
  constexpr int NKH = BK/32;
  constexpr int ASTG = TM*BK, BSTG = TN*BK;
  __shared__ unsigned short As[2*ASTG];
  __shared__ unsigned short Bs[2*BSTG];
  int tid = threadIdx.x;
  int lane = tid & 63, w = tid >> 6;
  int wr = w >> 1, wc = w & 1;
  int bid = blockIdx.x;
  int xcd = bid & 7, i = bid >> 3;
  int npx = nrow >> 3;
  int m0 = (xcd * npx + (i % npx)) * TM;
  int n0 = (i / npx) * TN;

  const unsigned short* ag[PA];
  const unsigned short* bg[PB];
  int aldst[PA], bldst[PB];
  #pragma unroll
  for (int p=0;p<PA;++p) {
    int ci = p*256 + tid;
    int row = ci / CH, cp = ci % CH;
    int cg = cp ^ swz<CH>(row);
    ag[p] = A + (size_t)(m0+row)*K + cg*8;
    aldst[p] = (p*256 + w*64)*8;
  }
  #pragma unroll
  for (int p=0;p<PB;++p) {
    int ci = p*256 + tid;
    int row = ci / CH, cp = ci % CH;
    int cg = cp ^ swz<CH>(row);
    bg[p] = Bt + (size_t)(n0+row)*K + cg*8;
    bldst[p] = (p*256 + w*64)*8;
  }

  int r = lane & 15, quad = lane >> 4;
  int aoff[NKH][AM], boff[NKH][AN];
  #pragma unroll
  for (int kh=0;kh<NKH;++kh) {
    int cb = kh*4 + quad;
    #pragma unroll
    for (int i2=0;i2<AM;++i2)
      aoff[kh][i2] = (wr*WM + i2*16 + r)*BK + ((cb ^ swz<CH>(r)) & (CH-1))*8;
    #pragma unroll
    for (int j=0;j<AN;++j)
      boff[kh][j] = (wc*WN + j*16 + r)*BK + ((cb ^ swz<CH>(r)) & (CH-1))*8;
  }

  f32x4 acc[AM][AN];
  #pragma unroll
  for (int i2=0;i2<AM;++i2)
    #pragma unroll
    for (int j=0;j<AN;++j)
      acc[i2][j] = (f32x4){0.f,0.f,0.f,0.f};

  #pragma unroll
  for (int p=0;p<PA;++p) gload_lds16(ag[p], &As[aldst[p]]);
  #pragma unroll
  for (int p=0;p<PB;++p) gload_lds16(bg[p], &Bs[bldst[p]]);

  int nk = K / BK;
  for (int ki = 0; ki < nk; ++ki) {
    __syncthreads();
    int cur = ki & 1, nxt = cur ^ 1;
    if (ki + 1 < nk) {
      int kk = (ki + 1) * BK;
      #pragma unroll
      for (int p=0;p<PA;++p) gload_lds16(ag[p] + kk, &As[nxt*ASTG + aldst[p]]);
      #pragma unroll
      for (int p=0;p<PB;++p) gload_lds16(bg[p] + kk, &Bs[nxt*BSTG + bldst[p]]);
    }
    #pragma unroll
    for (int kh=0;kh<NKH;++kh) {
      short8 af[AM], bfr[AN];
      #pragma unroll
      for (int i2=0;i2<AM;++i2) af[i2] = *(const short8*)&As[cur*ASTG + aoff[kh][i2]];
      #pragma unroll
      for (int j=0;j<AN;++j) bfr[j] = *(const short8*)&Bs[cur*BSTG + boff[kh][j]];
      #pragma unroll
      for (int i2=0;i2<AM;++i2)
        #pragma unroll
        for (int j=0;j<AN;++j)
          acc[i2][j] = __builtin_amdgcn_mfma_f32_16x16x32_bf16(af[i2], bfr[j], acc[i2][j], 0, 0, 0);
    }
  }

  // weighted-partial setup (next layer's decay), row-in-chunk = quad*4+reg
  float wnext = 0.f, invw = 0.f, pwbase = 0.f;
  if (EPI == 1 && partW) {
    wnext = decay_w(kvec, wl);
    invw = 1.0f / wnext;
    pwbase = 1.0f;
    for (int q = 0; q < 15 - quad*4; ++q) pwbase *= wnext;  // w^(15-quad*4)
  }

  #pragma unroll
  for (int i2=0;i2<AM;++i2) {
    int rowb = m0 + wr*WM + i2*16 + quad*4;
    #pragma unroll
    for (int j=0;j<AN;++j) {
      int col = n0 + wc*WN + j*16 + r;
      float bv = 0.f;
      if (EPI != 2) bv = bias[col];
      float ps = 0.f, psW = 0.f, pw = pwbase;
      #pragma unroll
      for (int reg=0;reg<4;++reg) {
        size_t idx = (size_t)(rowb + reg) * N + col;
        float z = acc[i2][j][reg] + bv;
        if (EPI == 0) {
          Cb[idx] = f2bf(gelu_f(z));
        } else if (EPI == 1) {
          float hv = C[idx] + z;
          C[idx] = hv;
          ps += hv;
          if (partW) { psW += pw * hv; pw *= invw; }
          if (Cb) Cb[idx] = f2bf(hv);
        } else {
          C[idx] = z;
        }
      }
      if (EPI == 1 && part) {
        ps += __shfl_xor(ps, 16);
        ps += __shfl_xor(ps, 32);
        if (partW) {
          psW += __shfl_xor(psW, 16);
          psW += __shfl_xor(psW, 32);
        }
        if (quad == 0) {
          int chunk = (m0 + wr*WM + i2*16) >> 4;   // TSF=16
          part[(size_t)chunk * N + col] = ps;
          if (partW) partW[(size_t)chunk * N + col] = psW;
        }
      }
    }
  }
}

extern "C" void kernel_launch(void* const* d_in, const int* in_sizes, int n_in,
                              void* d_out, int out_size, void* d_ws, size_t ws_size,
                              hipStream_t stream) {
  const int*   x     = (const int*)  d_in[0];
  const float* embed = (const float*)d_in[1];
  const float* kvec  = (const float*)d_in[2];
  const float* g     = (const float*)d_in[3];
  const float* bt    = (const float*)d_in[4];
  const float* W1    = (const float*)d_in[5];
  const float* b1    = (const float*)d_in[6];
  const float* W2    = (const float*)d_in[7];
  const float* b2    = (const float*)d_in[8];
  float* out = (float*)d_out;

  const size_t NTD = (size_t)Bc * Tc * Dc;   // 4,194,304
  const size_t NTH = (size_t)Bc * Tc * Hc;   // 16,777,216
  char* wsb = (char*)d_ws;
  float* h      = (float*)wsb;                wsb += NTD*4;               // 16MB
  float* tmpA   = (float*)wsb;                wsb += NTD*4;               // 16MB (th)
  float* partA  = (float*)wsb;                wsb += (size_t)Bc*NCF*Dc*4; // 1MB
  float* partB  = (float*)wsb;                wsb += (size_t)Bc*NCF*Dc*4; // 1MB
  float* partW  = (float*)wsb;                wsb += (size_t)Bc*NCF*Dc*4; // 1MB
  unsigned short* yb   = (unsigned short*)wsb; wsb += NTD*2;              // 8MB
  unsigned short* a1b  = (unsigned short*)wsb; wsb += NTH*2;              // 32MB
  unsigned short* hb   = (unsigned short*)wsb; wsb += NTD*2;              // 8MB
  unsigned short* W1t  = (unsigned short*)wsb; wsb += (size_t)3*Dc*Hc*2;  // 6MB
  unsigned short* W2t  = (unsigned short*)wsb; wsb += (size_t)3*Dc*Hc*2;  // 6MB
  unsigned short* emb  = (unsigned short*)wsb; wsb += (size_t)Vc*Dc*2;

  // merged weight prep (1 dispatch)
  wprep<<<dim3(6144 + (Vc*Dc+255)/256), 256, 0, stream>>>(
      W1, W1t, W2, W2t, embed, emb);

  // prologue
  embed_part<<<dim3(NCF, Bc), 1024, 0, stream>>>(x, embed, tmpA, partA);
  part_prefix<<<dim3(256), 512, 0, stream>>>(partA);
  bd_apply<<<dim3(NCF, Bc), 512, 0, stream>>>(tmpA, partA, x, embed, h,
                                              partB, partW, kvec);
  part_prefix<<<dim3(256), 512, 0, stream>>>(partB);

  for (int l = 0; l < 3; ++l) {
    mag_scan_ln<<<dim3(NCF, Bc), 512, 0, stream>>>(h, partB, partW, kvec, l,
                                                   g, bt, yb);
    // z = gelu(y @ W1 + b1): M=8192 N=2048 K=512; 64x64 BK=64 -> 4096 blocks
    mgemm<0,64,64,64><<<dim3(128*(Hc/64)), 256, 0, stream>>>(
        yb, W1t + (size_t)l*Hc*Dc, b1 + (size_t)l*Hc, nullptr, a1b,
        nullptr, nullptr, kvec, 0, Hc, Dc, 128);
    // h += z @ W2 + b2 (+ raw & weighted chunk partials for layer l+1)
    mgemm<1,64,64,64><<<dim3(128*(Dc/64)), 256, 0, stream>>>(
        a1b, W2t + (size_t)l*Dc*Hc, b2 + (size_t)l*Dc, h,
        (l == 2) ? hb : nullptr,
        (l < 2) ? partB : nullptr, (l < 2) ? partW : nullptr, kvec, l + 1,
        Dc, Hc, 128);
    if (l < 2) part_prefix<<<dim3(256), 512, 0, stream>>>(partB);
  }
  // out = h @ embed^T: M=8192 N=256 K=512; 64x64 tiles, nrow=128
  mgemm<2,64,64,32><<<dim3(128*(Vc/64)), 256, 0, stream>>>(
      hb, emb, nullptr, out, nullptr, nullptr, nullptr, kvec, 0,
      Vc, Dc, 128);
}